// Round 2
// baseline (92.314 us; speedup 1.0000x reference)
//
#include <hip/hip_runtime.h>

#define NQ 4
#define DIM 16
#define E 4

// Round 15 (= R14 resubmit; R14 bench was an infra failure, no signal).
// Keep R13's scalar-pipe H delivery (s_load_dwordx4, zero vector cost) but
// amortize it: E=4 elements per thread share every H row fetch. Per-wave H
// traffic /4, per-wave FMA ILP x4 (16 independent chains). u_i recomputed
// per-i from 4 stored trig regs to keep VGPR ~85 (>=4 w/SIMD).
// Only delta vs R14: __sincosf -> __sinf/__cosf (the verified-R12 idiom).

typedef __attribute__((ext_vector_type(4))) float fv4;

constexpr int PA[10] = {0,0,0,0,1,1,1,2,2,3};
constexpr int PC[10] = {0,1,2,3,1,2,3,2,3,3};

// TC[ac][i]: coefficient (x1/4) of basis u_i (i = 3*i0+i1, f = {1, cos, sin})
// in hh_{PA[ac]} * hh_{PC[ac]}. Same matrix applies to the ll side (x2,x3).
__device__ constexpr float TC[10][9] = {
    {1, 1, 0,  1, 1, 0,  0, 0, 0},   // (0,0): (1+c0)(1+c1)
    {0, 0, 1,  0, 0, 1,  0, 0, 0},   // (0,1): (1+c0) s1
    {0, 0, 0,  0, 0, 0,  1, 1, 0},   // (0,2): s0 (1+c1)
    {0, 0, 0,  0, 0, 0,  0, 0, 1},   // (0,3): s0 s1
    {1,-1, 0,  1,-1, 0,  0, 0, 0},   // (1,1): (1+c0)(1-c1)
    {0, 0, 0,  0, 0, 0,  0, 0, 1},   // (1,2): s0 s1
    {0, 0, 0,  0, 0, 0,  1,-1, 0},   // (1,3): s0 (1-c1)
    {1, 1, 0, -1,-1, 0,  0, 0, 0},   // (2,2): (1-c0)(1+c1)
    {0, 0, 1,  0, 0,-1,  0, 0, 0},   // (2,3): (1-c0) s1
    {1,-1, 0, -1, 1, 0,  0, 0, 0},   // (3,3): (1-c0)(1-c1)
};

__global__ void __launch_bounds__(128)
qlayer_prep(const float* __restrict__ weights, fv4* __restrict__ hw)
{
    __shared__ __align__(16) float2 WT[DIM][DIM];   // WT[j][i] = W[i][j]
    __shared__ __align__(16) fv4 G4[100];

    // ---- phase 1: threads 0..15 build W columns (verified R1-R12) ----
    if (threadIdx.x < DIM) {
        const int k = threadIdx.x;
        float sre[DIM], sim[DIM];
#pragma unroll
        for (int i = 0; i < DIM; ++i) { sre[i] = (i == k) ? 1.f : 0.f; sim[i] = 0.f; }
#pragma unroll
        for (int l = 0; l < 3; ++l) {
#pragma unroll
            for (int p = 0; p < NQ; ++p) {
                const float h = 0.5f * weights[l * NQ + p];
                const float s = __sinf(h), c = __cosf(h);
                const int mask = 1 << (NQ - 1 - p);
#pragma unroll
                for (int i = 0; i < DIM; ++i) {
                    if (i & mask) continue;
                    const int jj = i | mask;
                    const float ar = sre[i], ai = sim[i];
                    const float br = sre[jj], bi = sim[jj];
                    sre[i]  = c * ar + s * bi;
                    sim[i]  = c * ai - s * br;
                    sre[jj] = c * br + s * ai;
                    sim[jj] = c * bi - s * ar;
                }
            }
#pragma unroll
            for (int p = 0; p < NQ; ++p) {
                const int t = (p + 1) % NQ;
                float tr[DIM], ti[DIM];
#pragma unroll
                for (int i = 0; i < DIM; ++i) {
                    const int src = i ^ ((((i >> (NQ - 1 - p)) & 1)) << (NQ - 1 - t));
                    tr[i] = sre[src]; ti[i] = sim[src];
                }
#pragma unroll
                for (int i = 0; i < DIM; ++i) { sre[i] = tr[i]; sim[i] = ti[i]; }
            }
        }
#pragma unroll
        for (int i = 0; i < DIM; ++i) WT[k][i] = make_float2(sre[i], sim[i]);
    }
    __syncthreads();

    // ---- phase 2: threads 0..99 build folded G table (verified R2-R12) ----
    if (threadIdx.x < 100) {
        const int ac = threadIdx.x / 10, bd = threadIdx.x % 10;
        const int a = PA[ac], c = PC[ac], b = PA[bd], d = PC[bd];

        auto evalS = [&](int j, int k, float* sv) {
            float ar[4] = {0,0,0,0}, ai[4] = {0,0,0,0};
#pragma unroll
            for (int i = 0; i < DIM; ++i) {
                const float2 wj = WT[j][i], wk = WT[k][i];
                const float pr = wj.x * wk.x + wj.y * wk.y;
                const float pi = wj.x * wk.y - wj.y * wk.x;
#pragma unroll
                for (int q = 0; q < 4; ++q) {
                    const float s = ((i >> (3 - q)) & 1) ? -1.f : 1.f;
                    ar[q] += s * pr; ai[q] += s * pi;
                }
            }
            const int m = (__builtin_popcount(j) - __builtin_popcount(k)) & 3;
#pragma unroll
            for (int q = 0; q < 4; ++q)
                sv[q] = (m == 0) ? ar[q] : (m == 1) ? -ai[q] : (m == 2) ? -ar[q] : ai[q];
        };

        float s1[4], s2[4];
        evalS(4 * a + b, 4 * c + d, s1);
        evalS(4 * a + d, 4 * c + b, s2);
        const float u = ((a < c) ? 2.f : 1.f) * ((b < d) ? 1.f : 0.5f);
        fv4 gv; gv.x = u*(s1[0]+s2[0]); gv.y = u*(s1[1]+s2[1]);
        gv.z = u*(s1[2]+s2[2]); gv.w = u*(s1[3]+s2[3]);
        G4[ac * 10 + bd] = gv;
    }
    __syncthreads();

    // ---- phase 3: threads 0..80 basis change H = (1/16) T G T^T (verified R12) ----
    if (threadIdx.x < 81) {
        const int i = threadIdx.x / 9, j = threadIdx.x % 9;
        fv4 acc = (fv4)(0.f);
#pragma unroll
        for (int ac = 0; ac < 10; ++ac) {
            const float ti = TC[ac][i];
            fv4 tj = (fv4)(0.f);
#pragma unroll
            for (int bd = 0; bd < 10; ++bd)
                tj += G4[ac * 10 + bd] * TC[bd][j];
            acc += tj * ti;
        }
        hw[i * 9 + j] = acc * 0.0625f;
    }
}

__global__ void __launch_bounds__(256)
qlayer_main(const float4* __restrict__ x,
            const fv4* __restrict__ hw,
            fv4* __restrict__ out, int B)
{
    const int base = blockIdx.x * (256 * E) + threadIdx.x;

    float uc0[E], us0[E], uc1[E], us1[E];   // u-side trig (u_i recomputed per i)
    float v[E][8];                          // v-side full basis
    fv4  o[E];

#pragma unroll
    for (int e = 0; e < E; ++e) {
        const int gi = base + 256 * e;
        const float4 xv = (gi < B) ? x[gi] : make_float4(0.f, 0.f, 0.f, 0.f);
        const float c0 = __cosf(xv.x), s0 = __sinf(xv.x);
        const float c1 = __cosf(xv.y), s1 = __sinf(xv.y);
        const float c2 = __cosf(xv.z), s2 = __sinf(xv.z);
        const float c3 = __cosf(xv.w), s3 = __sinf(xv.w);
        uc0[e] = c0; us0[e] = s0;
        uc1[e] = c1; us1[e] = s1;
        v[e][0] = c3;       v[e][1] = s3;       v[e][2] = c2;
        v[e][3] = c2 * c3;  v[e][4] = c2 * s3;
        v[e][5] = s2;       v[e][6] = s2 * c3;  v[e][7] = s2 * s3;
    }

#pragma unroll
    for (int i = 0; i < 9; ++i) {
        // One row of H fetched once per wave (s_load_dwordx4, scalar pipe),
        // consumed by E=4 elements -> per-element H cost /4 vs R13.
        fv4 h[9];
#pragma unroll
        for (int j = 0; j < 9; ++j) h[j] = hw[i * 9 + j];

#pragma unroll
        for (int e = 0; e < E; ++e) {
            fv4 t = h[0];                    // j = 0 (v_0 = 1)
#pragma unroll
            for (int j = 1; j < 9; ++j)
                t += h[j] * v[e][j - 1];

            if (i == 0) {
                o[e] = t;                    // u_0 = 1
            } else {
                const float ue =
                    (i == 1) ? uc1[e] :
                    (i == 2) ? us1[e] :
                    (i == 3) ? uc0[e] :
                    (i == 4) ? uc0[e] * uc1[e] :
                    (i == 5) ? uc0[e] * us1[e] :
                    (i == 6) ? us0[e] :
                    (i == 7) ? us0[e] * uc1[e] :
                               us0[e] * us1[e];
                o[e] += t * ue;
            }
        }
    }

#pragma unroll
    for (int e = 0; e < E; ++e) {
        const int gi = base + 256 * e;
        if (gi < B) out[gi] = o[e];
    }
}

extern "C" void kernel_launch(void* const* d_in, const int* in_sizes, int n_in,
                              void* d_out, int out_size, void* d_ws, size_t ws_size,
                              hipStream_t stream)
{
    const float4* x = (const float4*)d_in[0];
    const float* w  = (const float*)d_in[1];
    fv4* out        = (fv4*)d_out;
    fv4* hw         = (fv4*)d_ws;     // 81 * 16 B = 1296 B
    const int B = in_sizes[0] / NQ;

    qlayer_prep<<<1, 128, 0, stream>>>(w, hw);

    const int per_block = 256 * E;
    const int grid = (B + per_block - 1) / per_block;
    qlayer_main<<<grid, 256, 0, stream>>>(x, hw, out, B);
}